// Round 7
// baseline (641.368 us; speedup 1.0000x reference)
//
#include <hip/hip_runtime.h>

#define XD 64
#define HD 128
#define RB 64           // rows per block (2 blocks/CU, LDS-limited)
#define NT 512          // 8 waves: 2 M-groups (wm) x 4 N-groups (wn)
#define BLOB 18432      // per-step blob: 16KB swizzled bf16 Wi' + 2KB scalars
#define N_STEP_CHUNKS 18

// LDS byte offsets (total 80384 <= 81920 -> 2 blocks/CU)
#define OFF_STEP0 0
#define OFF_STEP1 18432
#define OFF_H1    36864
#define OFF_H2    53248
#define OFF_OUT   69632
#define OFF_ZC    77824
#define OFF_BS1   78336
#define OFF_BS2   78848
#define OFF_PART  79360
#define SMEM_BYTES 80384

typedef __attribute__((ext_vector_type(8))) short short8;
typedef __attribute__((ext_vector_type(4))) float f32x4;
typedef __attribute__((ext_vector_type(2))) unsigned int u32x2;
typedef unsigned int u32;

__device__ __forceinline__ short f2bf(float f) {
    union { float f; unsigned u; } v; v.f = f;
    unsigned r = (v.u + 0x7FFFu + ((v.u >> 16) & 1u)) >> 16;  // RTNE
    return (short)r;
}
__device__ __forceinline__ float bf2f(short s) {
    union { float f; unsigned u; } v;
    v.u = ((unsigned)(unsigned short)s) << 16;
    return v.f;
}
__device__ __forceinline__ u32 cvtpk2(float a, float b) {   // 2 f32 -> packed 2xbf16, 1 instr
    u32 r;
    asm("v_cvt_pk_bf16_f32 %0, %1, %2" : "=v"(r) : "v"(a), "v"(b));
    return r;
}

// XOR-swizzled addressing: natural pitch, byte-offset bits 4..6 ^= row&7
__device__ __forceinline__ void* swz128(char* base, int row, int byteoff) {
    return base + row * 128 + (byteoff ^ ((row & 7) << 4));
}
__device__ __forceinline__ void* swz256(char* base, int row, int byteoff) {
    return base + row * 256 + (byteoff ^ ((row & 7) << 4));
}

__device__ __forceinline__ void gload16(const void* g, void* l) {
    __builtin_amdgcn_global_load_lds(
        (const __attribute__((address_space(1))) u32*)g,
        (__attribute__((address_space(3))) u32*)l, 16, 0, 0);
}

// ---------------- prep: fold mask into Wi, bf16-convert, pre-swizzle into blobs ----------------
__global__ void prep_kernel(const float* __restrict__ Wi, const float* __restrict__ M,
                            const float* __restrict__ bi, const float* __restrict__ wf,
                            const float* __restrict__ bf, char* __restrict__ ws)
{
    int idx = blockIdx.x * 256 + threadIdx.x;
    if (idx < XD * HD * 8) {                       // Wi' part: 64 steps x 128 n x 8 k-chunks
        int i  = idx >> 10;
        int n  = (idx >> 3) & 127;
        int kc = idx & 7;
        const float* src = Wi + ((size_t)i * HD + n) * (XD + 1) + kc * 8;
        short8 v;
        #pragma unroll
        for (int j = 0; j < 8; ++j) {
            int k = kc * 8 + j;
            float m = (k == i) ? 0.0f : M[k * XD + i];
            v[j] = f2bf(src[j] * m);
        }
        char* dst = ws + (size_t)i * BLOB + n * 128 + ((kc * 16) ^ ((n & 7) << 4));
        *(short8*)dst = v;
    } else {
        int r = idx - XD * HD * 8;
        if (r < XD * HD) {                          // scalars: wiz / bi / wf / bf
            int i = r >> 7, n = r & 127;
            float* d = (float*)(ws + (size_t)i * BLOB + 16384);
            d[n]       = Wi[((size_t)i * HD + n) * (XD + 1) + XD];  // z-column weight
            d[128 + n] = bi[i * HD + n];
            d[256 + n] = wf[i * HD + n];
            if (n == 0) d[384] = bf[i];
        }
    }
}

// ---------------- main persistent-tile kernel ----------------
// launch_bounds(NT,2): cap 256 VGPR so the allocator does NOT spill (R5 lesson:
// (NT,4) made it target the 64-VGPR step and spill all weight fragments).
// 2 blocks/CU is enforced by LDS (2 x 80384 <= 160 KiB); needs <=128 VGPR, ~92 expected.
__global__ __launch_bounds__(NT, 2) void gen_kernel(
    const float* __restrict__ x,   const float* __restrict__ z,
    const float* __restrict__ Ws1, const float* __restrict__ Ws2,
    const float* __restrict__ bs1, const float* __restrict__ bs2,
    const char*  __restrict__ blob, float* __restrict__ out)
{
    extern __shared__ char smem[];
    const int tid  = threadIdx.x;
    const int row0 = blockIdx.x * RB;
    const int wave = tid >> 6, lane = tid & 63;
    const int lg = lane >> 4, lc = lane & 15;
    const int wm = wave >> 2, wn = wave & 3;    // 2 M-groups x 4 N-groups

    char*  sH1  = smem + OFF_H1;
    char*  sH2  = smem + OFF_H2;
    char*  sOUT = smem + OFF_OUT;
    float* sZC  = (float*)(smem + OFF_ZC);
    float* sBS1 = (float*)(smem + OFF_BS1);
    float* sBS2 = (float*)(smem + OFF_BS2);
    float* sPART= (float*)(smem + OFF_PART);

    // ---- prologue ----
    for (int c = wave; c < N_STEP_CHUNKS; c += 8)                      // blob 0 -> STEP0
        gload16(blob + c * 1024 + lane * 16, smem + OFF_STEP0 + c * 1024);
    if (tid < RB)                                                       // z col 0
        sZC[tid] = z[(size_t)(row0 + tid) * XD + 0];
    {                                                                   // OUT <- x (bf16, swz)
        int r = tid >> 3, kc = tid & 7;
        const float* xs = x + (size_t)(row0 + r) * XD + kc * 8;
        short8 v;
        #pragma unroll
        for (int j = 0; j < 8; ++j) v[j] = f2bf(xs[j]);
        *(short8*)swz128(sOUT, r, kc * 16) = v;
    }
    if (tid < HD) { sBS1[tid] = bs1[tid]; sBS2[tid] = bs2[tid]; }

    // Ws1 / Ws2 fragments for this wave's n-range only: 32+32 VGPRs
    short8 BW1[2][4], BW2[2][4];
    #pragma unroll
    for (int t = 0; t < 2; ++t) {
        int n = wn * 32 + t * 16 + lc;
        #pragma unroll
        for (int s = 0; s < 4; ++s) {
            const float* p1 = Ws1 + n * HD + s * 32 + lg * 8;
            const float* p2 = Ws2 + n * HD + s * 32 + lg * 8;
            #pragma unroll
            for (int j = 0; j < 8; ++j) {
                BW1[t][s][j] = f2bf(p1[j]);
                BW2[t][s][j] = f2bf(p2[j]);
            }
        }
    }
    __syncthreads();

    float zreg = 0.f;
    for (int i = 0; i < XD; ++i) {
        char* sWIb = smem + ((i & 1) ? OFF_STEP1 : OFF_STEP0);
        char* sWIn = smem + ((i & 1) ? OFF_STEP0 : OFF_STEP1);
        const float* blobS = (const float*)(sWIb + 16384);
        float* zcur = sZC + (i & 1) * RB;
        float* znxt = sZC + ((i + 1) & 1) * RB;

        if (i + 1 < XD) {                                  // async-stage next blob + z
            const char* gb = blob + (size_t)(i + 1) * BLOB;
            for (int c = wave; c < N_STEP_CHUNKS; c += 8)
                gload16(gb + c * 1024 + lane * 16, sWIn + c * 1024);
            if (tid < RB) zreg = z[(size_t)(row0 + tid) * XD + (i + 1)];
        }

        // ---- G1 (swapped, N-split): h1 = relu([out*mask | z] @ Wi'^T + bi) ----
        short8 aW[2][2];
        #pragma unroll
        for (int t = 0; t < 2; ++t) {
            int n = wn * 32 + t * 16 + lc;
            aW[t][0] = *(const short8*)swz128(sWIb, n, lg * 16);
            aW[t][1] = *(const short8*)swz128(sWIb, n, 64 + lg * 16);
        }
        #pragma unroll
        for (int m = 0; m < 2; ++m) {
            int r = wm * 32 + m * 16 + lc;
            short8 b0 = *(const short8*)swz128(sOUT, r, lg * 16);
            short8 b1 = *(const short8*)swz128(sOUT, r, 64 + lg * 16);
            float zm = zcur[r];
            #pragma unroll
            for (int t = 0; t < 2; ++t) {
                int nb = wn * 32 + t * 16;
                f32x4 wiz = *(const f32x4*)&blobS[nb + lg * 4];
                f32x4 c   = *(const f32x4*)&blobS[128 + nb + lg * 4];   // bias as C-init
                c = __builtin_amdgcn_mfma_f32_16x16x32_bf16(aW[t][0], b0, c, 0, 0, 0);
                c = __builtin_amdgcn_mfma_f32_16x16x32_bf16(aW[t][1], b1, c, 0, 0, 0);
                float v0 = fmaxf(c[0] + zm * wiz[0], 0.f);
                float v1 = fmaxf(c[1] + zm * wiz[1], 0.f);
                float v2 = fmaxf(c[2] + zm * wiz[2], 0.f);
                float v3 = fmaxf(c[3] + zm * wiz[3], 0.f);
                u32x2 w = { cvtpk2(v0, v1), cvtpk2(v2, v3) };
                *(u32x2*)swz256(sH1, r, 2 * nb + lg * 8) = w;
            }
        }
        __syncthreads();   // bar1

        // ---- G2 (swapped, N-split, Ws1 regs): h2 = relu(h1 @ Ws1^T + bs1) ----
        #pragma unroll
        for (int m = 0; m < 2; ++m) {
            int r = wm * 32 + m * 16 + lc;
            short8 bH[4];
            #pragma unroll
            for (int s = 0; s < 4; ++s)
                bH[s] = *(const short8*)swz256(sH1, r, s * 64 + lg * 16);
            #pragma unroll
            for (int t = 0; t < 2; ++t) {
                int nb = wn * 32 + t * 16;
                f32x4 c = *(const f32x4*)&sBS1[nb + lg * 4];
                #pragma unroll
                for (int s = 0; s < 4; ++s)
                    c = __builtin_amdgcn_mfma_f32_16x16x32_bf16(BW1[t][s], bH[s], c, 0, 0, 0);
                u32x2 w = { cvtpk2(fmaxf(c[0], 0.f), fmaxf(c[1], 0.f)),
                            cvtpk2(fmaxf(c[2], 0.f), fmaxf(c[3], 0.f)) };
                *(u32x2*)swz256(sH2, r, 2 * nb + lg * 8) = w;
            }
        }
        __syncthreads();   // bar2

        // ---- G3 (swapped, N-split, Ws2 regs) + wf-dot partials ----
        #pragma unroll
        for (int m = 0; m < 2; ++m) {
            int r = wm * 32 + m * 16 + lc;
            short8 bH[4];
            #pragma unroll
            for (int s = 0; s < 4; ++s)
                bH[s] = *(const short8*)swz256(sH2, r, s * 64 + lg * 16);
            float op = 0.f;
            #pragma unroll
            for (int t = 0; t < 2; ++t) {
                int nb = wn * 32 + t * 16;
                f32x4 c = *(const f32x4*)&sBS2[nb + lg * 4];
                #pragma unroll
                for (int s = 0; s < 4; ++s)
                    c = __builtin_amdgcn_mfma_f32_16x16x32_bf16(BW2[t][s], bH[s], c, 0, 0, 0);
                f32x4 wf4 = *(const f32x4*)&blobS[256 + nb + lg * 4];
                op += fmaxf(c[0], 0.f) * wf4[0];
                op += fmaxf(c[1], 0.f) * wf4[1];
                op += fmaxf(c[2], 0.f) * wf4[2];
                op += fmaxf(c[3], 0.f) * wf4[3];
            }
            op += __shfl_xor(op, 16, 64);      // reduce over lg
            op += __shfl_xor(op, 32, 64);
            if (lg == 0) sPART[wn * RB + r] = op;
        }
        __syncthreads();   // bar3: partials ready

        // ---- reduce 4 wn-partials, sigmoid, write OUT col i ----
        if (tid < RB) {
            float p = sPART[tid] + sPART[RB + tid] + sPART[2*RB + tid] + sPART[3*RB + tid]
                      + blobS[384];
            float o = 1.0f / (1.0f + __expf(-p));
            *(short*)swz128(sOUT, tid, 2 * i) = f2bf(o);
            if (i + 1 < XD) znxt[tid] = zreg;  // commit prefetched z
        }
        __syncthreads();   // bar4: OUT/z ready; also drains staging
    }

    // ---- epilogue ----
    {
        int r = tid >> 3, kc = tid & 7;
        short8 v = *(const short8*)swz128(sOUT, r, kc * 16);
        float* o = out + (size_t)(row0 + r) * XD + kc * 8;
        #pragma unroll
        for (int j = 0; j < 8; ++j) o[j] = bf2f(v[j]);
    }
}

extern "C" void kernel_launch(void* const* d_in, const int* in_sizes, int n_in,
                              void* d_out, int out_size, void* d_ws, size_t ws_size,
                              hipStream_t stream) {
    const float* x   = (const float*)d_in[0];
    const float* z   = (const float*)d_in[1];
    const float* M   = (const float*)d_in[2];
    const float* Wi  = (const float*)d_in[3];
    const float* bi  = (const float*)d_in[4];
    const float* Ws1 = (const float*)d_in[5];
    const float* bs1 = (const float*)d_in[6];
    const float* Ws2 = (const float*)d_in[7];
    const float* bs2 = (const float*)d_in[8];
    const float* wf  = (const float*)d_in[9];
    const float* bf  = (const float*)d_in[10];
    float* outp = (float*)d_out;
    char*  ws   = (char*)d_ws;

    prep_kernel<<<288, 256, 0, stream>>>(Wi, M, bi, wf, bf, ws);

    hipFuncSetAttribute(reinterpret_cast<const void*>(gen_kernel),
                        hipFuncAttributeMaxDynamicSharedMemorySize, SMEM_BYTES);
    gen_kernel<<<65536 / RB, NT, SMEM_BYTES, stream>>>(
        x, z, Ws1, Ws2, bs1, bs2, ws, outp);
}

// Round 8
// 550.086 us; speedup vs baseline: 1.1659x; 1.1659x over previous
//
#include <hip/hip_runtime.h>

#define XD 64
#define HD 128
#define RB 64           // rows per block
#define NT 256          // 4 waves: 1 M-group x 4 N-groups (wn)
#define BLOB 18432      // per-step blob: 16KB swizzled bf16 Wi' + 2KB scalars
#define N_STEP_CHUNKS 18

// LDS byte offsets (total 80384 -> 2 blocks/CU; 2x80384=160768 <= 163840)
#define OFF_STEP0 0
#define OFF_STEP1 18432
#define OFF_H1    36864
#define OFF_H2    53248
#define OFF_OUT   69632
#define OFF_ZC    77824
#define OFF_BS1   78336
#define OFF_BS2   78848
#define OFF_PART  79360
#define SMEM_BYTES 80384

typedef __attribute__((ext_vector_type(8))) short short8;
typedef __attribute__((ext_vector_type(4))) float f32x4;
typedef __attribute__((ext_vector_type(2))) unsigned int u32x2;
typedef unsigned int u32;

__device__ __forceinline__ short f2bf(float f) {
    union { float f; unsigned u; } v; v.f = f;
    unsigned r = (v.u + 0x7FFFu + ((v.u >> 16) & 1u)) >> 16;  // RTNE
    return (short)r;
}
__device__ __forceinline__ float bf2f(short s) {
    union { float f; unsigned u; } v;
    v.u = ((unsigned)(unsigned short)s) << 16;
    return v.f;
}
__device__ __forceinline__ u32 cvtpk2(float a, float b) {   // 2 f32 -> packed 2xbf16, 1 instr
    u32 r;
    asm("v_cvt_pk_bf16_f32 %0, %1, %2" : "=v"(r) : "v"(a), "v"(b));
    return r;
}

// XOR-swizzled addressing: natural pitch, byte-offset bits 4..6 ^= row&7
__device__ __forceinline__ void* swz128(char* base, int row, int byteoff) {
    return base + row * 128 + (byteoff ^ ((row & 7) << 4));
}
__device__ __forceinline__ void* swz256(char* base, int row, int byteoff) {
    return base + row * 256 + (byteoff ^ ((row & 7) << 4));
}

__device__ __forceinline__ void gload16(const void* g, void* l) {
    __builtin_amdgcn_global_load_lds(
        (const __attribute__((address_space(1))) u32*)g,
        (__attribute__((address_space(3))) u32*)l, 16, 0, 0);
}

// ---------------- prep: fold mask into Wi, bf16-convert, pre-swizzle into blobs ----------------
__global__ void prep_kernel(const float* __restrict__ Wi, const float* __restrict__ M,
                            const float* __restrict__ bi, const float* __restrict__ wf,
                            const float* __restrict__ bf, char* __restrict__ ws)
{
    int idx = blockIdx.x * 256 + threadIdx.x;
    if (idx < XD * HD * 8) {                       // Wi' part: 64 steps x 128 n x 8 k-chunks
        int i  = idx >> 10;
        int n  = (idx >> 3) & 127;
        int kc = idx & 7;
        const float* src = Wi + ((size_t)i * HD + n) * (XD + 1) + kc * 8;
        short8 v;
        #pragma unroll
        for (int j = 0; j < 8; ++j) {
            int k = kc * 8 + j;
            float m = (k == i) ? 0.0f : M[k * XD + i];
            v[j] = f2bf(src[j] * m);
        }
        char* dst = ws + (size_t)i * BLOB + n * 128 + ((kc * 16) ^ ((n & 7) << 4));
        *(short8*)dst = v;
    } else {
        int r = idx - XD * HD * 8;
        if (r < XD * HD) {                          // scalars: wiz / bi / wf / bf
            int i = r >> 7, n = r & 127;
            float* d = (float*)(ws + (size_t)i * BLOB + 16384);
            d[n]       = Wi[((size_t)i * HD + n) * (XD + 1) + XD];  // z-column weight
            d[128 + n] = bi[i * HD + n];
            d[256 + n] = wf[i * HD + n];
            if (n == 0) d[384] = bf[i];
        }
    }
}

// ---------------- main persistent-tile kernel ----------------
// 4-wave blocks, 2 blocks/CU (LDS: 2x80384 <= 160KiB; VGPR: need ~106 <= 128 cap
// from launch_bounds(256,2) under the empirical 256-wave-reg/SIMD budget;
// R5/R7 A/B established: VGPR=64 -> 2 blocks, VGPR=92 w/ 8-wave blocks -> 1 block).
// Two independent barrier domains per CU = the R5 overlap win without its spill.
__global__ __launch_bounds__(NT, 2) void gen_kernel(
    const float* __restrict__ x,   const float* __restrict__ z,
    const float* __restrict__ Ws1, const float* __restrict__ Ws2,
    const float* __restrict__ bs1, const float* __restrict__ bs2,
    const char*  __restrict__ blob, float* __restrict__ out)
{
    extern __shared__ char smem[];
    const int tid  = threadIdx.x;
    const int row0 = blockIdx.x * RB;
    const int wave = tid >> 6, lane = tid & 63;
    const int lg = lane >> 4, lc = lane & 15;
    const int wn = wave;                        // 4 N-groups, single M-group

    char*  sH1  = smem + OFF_H1;
    char*  sH2  = smem + OFF_H2;
    char*  sOUT = smem + OFF_OUT;
    float* sZC  = (float*)(smem + OFF_ZC);
    float* sBS1 = (float*)(smem + OFF_BS1);
    float* sBS2 = (float*)(smem + OFF_BS2);
    float* sPART= (float*)(smem + OFF_PART);

    // ---- prologue ----
    for (int c = wave; c < N_STEP_CHUNKS; c += 4)                      // blob 0 -> STEP0
        gload16(blob + c * 1024 + lane * 16, smem + OFF_STEP0 + c * 1024);
    if (tid < RB)                                                       // z col 0
        sZC[tid] = z[(size_t)(row0 + tid) * XD + 0];
    for (int c = tid; c < RB * 8; c += NT) {                            // OUT <- x (bf16, swz)
        int r = c >> 3, kc = c & 7;
        const float* xs = x + (size_t)(row0 + r) * XD + kc * 8;
        short8 v;
        #pragma unroll
        for (int j = 0; j < 8; ++j) v[j] = f2bf(xs[j]);
        *(short8*)swz128(sOUT, r, kc * 16) = v;
    }
    if (tid < HD) { sBS1[tid] = bs1[tid]; sBS2[tid] = bs2[tid]; }

    // Ws1 / Ws2 fragments for this wave's n-range only: 32+32 VGPRs
    short8 BW1[2][4], BW2[2][4];
    #pragma unroll
    for (int t = 0; t < 2; ++t) {
        int n = wn * 32 + t * 16 + lc;
        #pragma unroll
        for (int s = 0; s < 4; ++s) {
            const float* p1 = Ws1 + n * HD + s * 32 + lg * 8;
            const float* p2 = Ws2 + n * HD + s * 32 + lg * 8;
            #pragma unroll
            for (int j = 0; j < 8; ++j) {
                BW1[t][s][j] = f2bf(p1[j]);
                BW2[t][s][j] = f2bf(p2[j]);
            }
        }
    }
    __syncthreads();

    float zreg = 0.f;
    for (int i = 0; i < XD; ++i) {
        char* sWIb = smem + ((i & 1) ? OFF_STEP1 : OFF_STEP0);
        char* sWIn = smem + ((i & 1) ? OFF_STEP0 : OFF_STEP1);
        const float* blobS = (const float*)(sWIb + 16384);
        float* zcur = sZC + (i & 1) * RB;
        float* znxt = sZC + ((i + 1) & 1) * RB;

        if (i + 1 < XD) {                                  // async-stage next blob + z
            const char* gb = blob + (size_t)(i + 1) * BLOB;
            for (int c = wave; c < N_STEP_CHUNKS; c += 4)
                gload16(gb + c * 1024 + lane * 16, sWIn + c * 1024);
            if (tid < RB) zreg = z[(size_t)(row0 + tid) * XD + (i + 1)];
        }

        // ---- G1 (swapped, N-split): h1 = relu([out*mask | z] @ Wi'^T + bi) ----
        short8 aW[2][2];
        #pragma unroll
        for (int t = 0; t < 2; ++t) {
            int n = wn * 32 + t * 16 + lc;
            aW[t][0] = *(const short8*)swz128(sWIb, n, lg * 16);
            aW[t][1] = *(const short8*)swz128(sWIb, n, 64 + lg * 16);
        }
        #pragma unroll
        for (int m = 0; m < 4; ++m) {
            int r = m * 16 + lc;
            short8 b0 = *(const short8*)swz128(sOUT, r, lg * 16);
            short8 b1 = *(const short8*)swz128(sOUT, r, 64 + lg * 16);
            float zm = zcur[r];
            #pragma unroll
            for (int t = 0; t < 2; ++t) {
                int nb = wn * 32 + t * 16;
                f32x4 wiz = *(const f32x4*)&blobS[nb + lg * 4];
                f32x4 c   = *(const f32x4*)&blobS[128 + nb + lg * 4];   // bias as C-init
                c = __builtin_amdgcn_mfma_f32_16x16x32_bf16(aW[t][0], b0, c, 0, 0, 0);
                c = __builtin_amdgcn_mfma_f32_16x16x32_bf16(aW[t][1], b1, c, 0, 0, 0);
                float v0 = fmaxf(c[0] + zm * wiz[0], 0.f);
                float v1 = fmaxf(c[1] + zm * wiz[1], 0.f);
                float v2 = fmaxf(c[2] + zm * wiz[2], 0.f);
                float v3 = fmaxf(c[3] + zm * wiz[3], 0.f);
                u32x2 w = { cvtpk2(v0, v1), cvtpk2(v2, v3) };
                *(u32x2*)swz256(sH1, r, 2 * nb + lg * 8) = w;
            }
        }
        __syncthreads();   // bar1

        // ---- G2 (swapped, N-split, Ws1 regs): h2 = relu(h1 @ Ws1^T + bs1) ----
        #pragma unroll
        for (int m = 0; m < 4; ++m) {
            int r = m * 16 + lc;
            short8 bH[4];
            #pragma unroll
            for (int s = 0; s < 4; ++s)
                bH[s] = *(const short8*)swz256(sH1, r, s * 64 + lg * 16);
            #pragma unroll
            for (int t = 0; t < 2; ++t) {
                int nb = wn * 32 + t * 16;
                f32x4 c = *(const f32x4*)&sBS1[nb + lg * 4];
                #pragma unroll
                for (int s = 0; s < 4; ++s)
                    c = __builtin_amdgcn_mfma_f32_16x16x32_bf16(BW1[t][s], bH[s], c, 0, 0, 0);
                u32x2 w = { cvtpk2(fmaxf(c[0], 0.f), fmaxf(c[1], 0.f)),
                            cvtpk2(fmaxf(c[2], 0.f), fmaxf(c[3], 0.f)) };
                *(u32x2*)swz256(sH2, r, 2 * nb + lg * 8) = w;
            }
        }
        __syncthreads();   // bar2

        // ---- G3 (swapped, N-split, Ws2 regs) + wf-dot partials ----
        #pragma unroll
        for (int m = 0; m < 4; ++m) {
            int r = m * 16 + lc;
            short8 bH[4];
            #pragma unroll
            for (int s = 0; s < 4; ++s)
                bH[s] = *(const short8*)swz256(sH2, r, s * 64 + lg * 16);
            float op = 0.f;
            #pragma unroll
            for (int t = 0; t < 2; ++t) {
                int nb = wn * 32 + t * 16;
                f32x4 c = *(const f32x4*)&sBS2[nb + lg * 4];
                #pragma unroll
                for (int s = 0; s < 4; ++s)
                    c = __builtin_amdgcn_mfma_f32_16x16x32_bf16(BW2[t][s], bH[s], c, 0, 0, 0);
                f32x4 wf4 = *(const f32x4*)&blobS[256 + nb + lg * 4];
                op += fmaxf(c[0], 0.f) * wf4[0];
                op += fmaxf(c[1], 0.f) * wf4[1];
                op += fmaxf(c[2], 0.f) * wf4[2];
                op += fmaxf(c[3], 0.f) * wf4[3];
            }
            op += __shfl_xor(op, 16, 64);      // reduce over lg
            op += __shfl_xor(op, 32, 64);
            if (lg == 0) sPART[wn * RB + r] = op;
        }
        __syncthreads();   // bar3: partials ready

        // ---- reduce 4 wn-partials, sigmoid, write OUT col i ----
        if (tid < RB) {
            float p = sPART[tid] + sPART[RB + tid] + sPART[2*RB + tid] + sPART[3*RB + tid]
                      + blobS[384];
            float o = 1.0f / (1.0f + __expf(-p));
            *(short*)swz128(sOUT, tid, 2 * i) = f2bf(o);
            if (i + 1 < XD) znxt[tid] = zreg;  // commit prefetched z
        }
        __syncthreads();   // bar4: OUT/z ready; also drains staging
    }

    // ---- epilogue ----
    for (int c = tid; c < RB * 8; c += NT) {
        int r = c >> 3, kc = c & 7;
        short8 v = *(const short8*)swz128(sOUT, r, kc * 16);
        float* o = out + (size_t)(row0 + r) * XD + kc * 8;
        #pragma unroll
        for (int j = 0; j < 8; ++j) o[j] = bf2f(v[j]);
    }
}

extern "C" void kernel_launch(void* const* d_in, const int* in_sizes, int n_in,
                              void* d_out, int out_size, void* d_ws, size_t ws_size,
                              hipStream_t stream) {
    const float* x   = (const float*)d_in[0];
    const float* z   = (const float*)d_in[1];
    const float* M   = (const float*)d_in[2];
    const float* Wi  = (const float*)d_in[3];
    const float* bi  = (const float*)d_in[4];
    const float* Ws1 = (const float*)d_in[5];
    const float* bs1 = (const float*)d_in[6];
    const float* Ws2 = (const float*)d_in[7];
    const float* bs2 = (const float*)d_in[8];
    const float* wf  = (const float*)d_in[9];
    const float* bf  = (const float*)d_in[10];
    float* outp = (float*)d_out;
    char*  ws   = (char*)d_ws;

    prep_kernel<<<288, 256, 0, stream>>>(Wi, M, bi, wf, bf, ws);

    hipFuncSetAttribute(reinterpret_cast<const void*>(gen_kernel),
                        hipFuncAttributeMaxDynamicSharedMemorySize, SMEM_BYTES);
    gen_kernel<<<65536 / RB, NT, SMEM_BYTES, stream>>>(
        x, z, Ws1, Ws2, bs1, bs2, ws, outp);
}